// Round 4
// baseline (12645.898 us; speedup 1.0000x reference)
//
#include <hip/hip_runtime.h>
#include <math.h>

constexpr int H   = 512;
constexpr int B   = 512;
constexpr int T   = 256;
constexpr int F   = 8;
constexpr int HOR = 24;

typedef _Float16 f16;
typedef _Float16 f16x8 __attribute__((ext_vector_type(8)));
typedef float    f32x4 __attribute__((ext_vector_type(4)));

__device__ __forceinline__ float sigm(float x) { return 1.0f / (1.0f + expf(-x)); }

// ---------------------------------------------------------------------------
// Weight convert: fp32 [4H][H] gate-major rows (row = g*H + jh) -> fp16
// [2048][512] permuted rows n' = jh*4 + g. grid (512, 6).
__global__ __launch_bounds__(256)
void wconv_k(const float* __restrict__ s0, f16* __restrict__ d0,
             const float* __restrict__ s1, f16* __restrict__ d1,
             const float* __restrict__ s2, f16* __restrict__ d2,
             const float* __restrict__ s3, f16* __restrict__ d3,
             const float* __restrict__ s4, f16* __restrict__ d4,
             const float* __restrict__ s5, f16* __restrict__ d5)
{
    const float* src; f16* dst;
    switch (blockIdx.y) {
        case 0:  src = s0; dst = d0; break;
        case 1:  src = s1; dst = d1; break;
        case 2:  src = s2; dst = d2; break;
        case 3:  src = s3; dst = d3; break;
        case 4:  src = s4; dst = d4; break;
        default: src = s5; dst = d5; break;
    }
    int idx = (blockIdx.x * 256 + threadIdx.x) * 8;
    int np  = idx >> 9;
    int k   = idx & 511;
    int jh  = np >> 2, g = np & 3;
    const float* sp = src + (size_t)(g * H + jh) * H + k;
    f16 tmp[8];
    #pragma unroll
    for (int j = 0; j < 8; ++j) tmp[j] = (f16)sp[j];
    *(f16x8*)(dst + idx) = *(const f16x8*)tmp;
}

// ---------------------------------------------------------------------------
// Flag sync: producer group (32 blocks sharing bt) increments counter with
// agent-scope RELEASE (L2 writeback); consumer spins relaxed then ACQUIRE
// (L2 invalidate) so cross-XCD h data is fresh.
__device__ __forceinline__ void waitcnt_eq(int* p, int target)
{
    if (threadIdx.x == 0) {
        while (__hip_atomic_load(p, __ATOMIC_RELAXED, __HIP_MEMORY_SCOPE_AGENT) < target)
            __builtin_amdgcn_s_sleep(1);
        (void)__hip_atomic_load(p, __ATOMIC_ACQUIRE, __HIP_MEMORY_SCOPE_AGENT);
    }
    __syncthreads();
}

// ---------------------------------------------------------------------------
struct Chunk { f16x8 a0, a1, w0, w1; };

// A rows: kt<8 from A0, kt>=8 from A1 (K up to 1024). BM=64 fixed.
__device__ __forceinline__ Chunk load_chunk(int kt,
    const f16* __restrict__ A0, const f16* __restrict__ A1,
    const f16* __restrict__ W0, const f16* __restrict__ W1,
    int b0, int n0, int srow, int sch)
{
    const f16* Ap = (kt < 8) ? A0 : A1;
    const f16* Wp = (kt < 8) ? W0 : W1;
    const int  ko = ((kt < 8) ? kt : kt - 8) * 64;
    Chunk c;
    const f16* ap = Ap + (size_t)(b0 + srow) * H + ko + sch * 16;
    c.a0 = *(const f16x8*)ap;
    c.a1 = *(const f16x8*)(ap + 8);
    const f16* wp = Wp + (size_t)(n0 + srow) * H + ko + sch * 16;
    c.w0 = *(const f16x8*)wp;
    c.w1 = *(const f16x8*)(wp + 8);
    return c;
}

// Fused LSTM cell tile, 64 b-rows x 64 n', K = nkt*64 (nkt = 0, 8 or 16).
// xmode: 0 none; 1 enc0 x-path (F=8 fp32); 2 scalar from xptr[b*xstride];
//        3 scalar from LDS pred_s[bl].
__device__ void cell_body(int bt, int nt, char* smem,
    const f16* __restrict__ A0, const f16* __restrict__ A1,
    const f16* __restrict__ W0, const f16* __restrict__ W1, int nkt,
    const float* __restrict__ bih, const float* __restrict__ bhh,
    int xmode, const float* __restrict__ xptr, int xstride,
    const float* __restrict__ xw, const float* __restrict__ pred_s,
    float* __restrict__ cst, f16* __restrict__ hout)
{
    constexpr int ABUF = 64 * 72;                  // halfs per buffer slot
    f16*   As = (f16*)smem;                        // [2][64][72]
    f16*   Ws = (f16*)smem + 2 * ABUF;             // [2][64][72]
    float* zs = (float*)smem;                      // overlay after K-loop

    const int tid  = threadIdx.x;
    const int lane = tid & 63;
    const int wv   = tid >> 6;
    const int wm   = wv & 1;
    const int wn   = wv >> 1;
    const int r    = lane & 15;
    const int g4   = lane >> 4;
    const int b0   = bt * 64;
    const int n0   = nt * 64;
    const int jh0  = nt * 16;
    const int srow = tid >> 2, sch = tid & 3;

    f32x4 acc[2][2] = {};

    Chunk cur = {};
    if (nkt > 0) cur = load_chunk(0, A0, A1, W0, W1, b0, n0, srow, sch);

    for (int kt = 0; kt < nkt; ++kt) {
        const int p = kt & 1;
        f16* Ab = As + p * ABUF;
        f16* Wb = Ws + p * ABUF;
        *(f16x8*)(Ab + srow * 72 + sch * 16)     = cur.a0;
        *(f16x8*)(Ab + srow * 72 + sch * 16 + 8) = cur.a1;
        *(f16x8*)(Wb + srow * 72 + sch * 16)     = cur.w0;
        *(f16x8*)(Wb + srow * 72 + sch * 16 + 8) = cur.w1;
        __syncthreads();

        Chunk nxt = cur;
        if (kt + 1 < nkt)
            nxt = load_chunk(kt + 1, A0, A1, W0, W1, b0, n0, srow, sch);

        #pragma unroll
        for (int sub = 0; sub < 2; ++sub) {
            f16x8 bf0 = *(const f16x8*)(Wb + (wn * 32 + r)      * 72 + sub * 32 + g4 * 8);
            f16x8 bf1 = *(const f16x8*)(Wb + (wn * 32 + 16 + r) * 72 + sub * 32 + g4 * 8);
            f16x8 af0 = *(const f16x8*)(Ab + (wm * 32 + r)      * 72 + sub * 32 + g4 * 8);
            f16x8 af1 = *(const f16x8*)(Ab + (wm * 32 + 16 + r) * 72 + sub * 32 + g4 * 8);
            acc[0][0] = __builtin_amdgcn_mfma_f32_16x16x32_f16(af0, bf0, acc[0][0], 0, 0, 0);
            acc[0][1] = __builtin_amdgcn_mfma_f32_16x16x32_f16(af0, bf1, acc[0][1], 0, 0, 0);
            acc[1][0] = __builtin_amdgcn_mfma_f32_16x16x32_f16(af1, bf0, acc[1][0], 0, 0, 0);
            acc[1][1] = __builtin_amdgcn_mfma_f32_16x16x32_f16(af1, bf1, acc[1][1], 0, 0, 0);
        }
        cur = nxt;
    }

    __syncthreads();   // last frag reads drained before zs overlay
    #pragma unroll
    for (int fm = 0; fm < 2; ++fm)
        #pragma unroll
        for (int fn = 0; fn < 2; ++fn)
            #pragma unroll
            for (int j = 0; j < 4; ++j)
                zs[(wm * 32 + fm * 16 + g4 * 4 + j) * 68 +
                   (wn * 32 + fn * 16 + r)] = acc[fm][fn][j];
    __syncthreads();

    // epilogue: thread -> (4 b-rows, 1 jh); gates = 4 consecutive n'.
    const int jl = tid & 15;
    const int bq = tid >> 4;
    const int jh = jh0 + jl;

    float bsum[4];
    #pragma unroll
    for (int g = 0; g < 4; ++g) bsum[g] = bih[g * H + jh] + bhh[g * H + jh];

    #pragma unroll
    for (int bb = 0; bb < 4; ++bb) {
        const int bl = bq * 4 + bb;
        const int b  = b0 + bl;
        float4 z = *(const float4*)(zs + bl * 68 + jl * 4);
        float zi = z.x + bsum[0];
        float zf = z.y + bsum[1];
        float zg = z.z + bsum[2];
        float zo = z.w + bsum[3];
        if (xmode == 1) {
            const float* xr = xptr + (size_t)b * xstride;
            #pragma unroll
            for (int k = 0; k < F; ++k) {
                float xv = xr[k];
                zi += xv * xw[(0 * H + jh) * F + k];
                zf += xv * xw[(1 * H + jh) * F + k];
                zg += xv * xw[(2 * H + jh) * F + k];
                zo += xv * xw[(3 * H + jh) * F + k];
            }
        } else if (xmode == 2 || xmode == 3) {
            float xv = (xmode == 2) ? xptr[(size_t)b * xstride] : pred_s[bl];
            zi += xv * xw[0 * H + jh];
            zf += xv * xw[1 * H + jh];
            zg += xv * xw[2 * H + jh];
            zo += xv * xw[3 * H + jh];
        }
        size_t idx = (size_t)b * H + jh;
        float cold = cst[idx];
        float cn = sigm(zf) * cold + sigm(zi) * tanhf(zg);
        cst[idx] = cn;
        hout[idx] = (f16)(sigm(zo) * tanhf(cn));
    }
}

// ---------------------------------------------------------------------------
// pred for 64 rows of this bt: pred_s[row] = h1row . outW + outb.
// All 32 nt blocks compute redundantly; only nt==0 writes d_out[., oidx].
__device__ void compute_pred(int bt, int nt, const f16* __restrict__ h1src,
                             const float* __restrict__ outW,
                             const float* __restrict__ outb,
                             float* pred_s, float* __restrict__ dout, int oidx)
{
    const int row = threadIdx.x >> 2;
    const int q   = threadIdx.x & 3;
    const int b   = bt * 64 + row;
    const f16x8* hv = (const f16x8*)(h1src + (size_t)b * H + q * 128);
    const float* wr = outW + q * 128;
    float s = 0.f;
    #pragma unroll
    for (int k8 = 0; k8 < 16; ++k8) {
        f16x8 h8 = hv[k8];
        #pragma unroll
        for (int j = 0; j < 8; ++j) s += (float)h8[j] * wr[k8 * 8 + j];
    }
    s += __shfl_down(s, 2);
    s += __shfl_down(s, 1);
    if (q == 0) {
        float p = s + outb[0];
        pred_s[row] = p;
        if (nt == 0) dout[(size_t)b * HOR + oidx] = p;
    }
    __syncthreads();
}

// ---------------------------------------------------------------------------
struct PArgs {
    const f16 *wh0, *wih1, *whh1, *dwh0, *dwih1, *dwhh1;
    const float *x;
    const float *ebih0, *ebhh0, *ebih1, *ebhh1;
    const float *dbih0, *dbhh0, *dbih1, *dbhh1;
    const float *eWih0, *dWih0, *outW, *outb;
    f16 *h0ring, *h1ping, *h0dping, *h1dping;
    float *c0, *c1, *dout;
    int *cnt0, *cnt1, *cons0, *cnt0d, *cnt1d;
};

// Persistent kernel: 512 blocks (2/CU guaranteed: 37.1KB LDS, <=256 VGPR).
// Blocks [0,256): layer0 role; [256,512): layer1 role. bt=idx>>5, nt=idx&31.
// Groups of 32 blocks (same bt) produce 64 full rows of h; counters target 32.
__global__ __launch_bounds__(256, 2)
void persist_k(PArgs a)
{
    __shared__ __align__(16) char smem[37120];
    float* pred_s = (float*)(smem + 36864);
    const size_t BH = (size_t)B * H;
    const int bid = blockIdx.x;

    if (bid < 256) {
        const int bt = bid >> 5, nt = bid & 31;
        // ---- encoder layer0: h0(t) = cell(x(t), h0(t-1)) ----
        for (int t = 0; t < T; ++t) {
            if (t >= 1) waitcnt_eq(a.cnt0 + (t - 1) * 8 + bt, 32);   // h0(t-1) ready (also self-group barrier)
            if (t >= 4) waitcnt_eq(a.cons0 + (t - 4) * 8 + bt, 32);  // ring slot free of L1 readers
            const f16* hp = a.h0ring + (size_t)((t + 3) & 3) * BH;   // h0(t-1)
            cell_body(bt, nt, smem, hp, hp, a.wh0, a.wh0, (t == 0) ? 0 : 8,
                      a.ebih0, a.ebhh0, 1, a.x + (size_t)t * F, T * F, a.eWih0,
                      nullptr, a.c0, a.h0ring + (size_t)(t & 3) * BH);
            __syncthreads();
            if (threadIdx.x == 0)
                __hip_atomic_fetch_add(a.cnt0 + t * 8 + bt, 1,
                                       __ATOMIC_RELEASE, __HIP_MEMORY_SCOPE_AGENT);
        }
        // ---- decoder layer0 (+ pred head) ----
        for (int td = 0; td <= HOR; ++td) {
            if (td == 0) {
                waitcnt_eq(a.cnt0 + 255 * 8 + bt, 32);               // enc h0 final (self-group)
            } else {
                waitcnt_eq(a.cnt1d + (td - 1) * 8 + bt, 32);         // h1d(td-1) rows ready
                compute_pred(bt, nt, a.h1dping + (size_t)((td + 1) & 1) * BH,
                             a.outW, a.outb, pred_s, a.dout, td - 1);
            }
            if (td == HOR) break;
            if (td >= 1) waitcnt_eq(a.cnt0d + (td - 1) * 8 + bt, 32); // h0d(td-1) ready (self-group)
            const f16* hp = (td == 0) ? a.h0ring + (size_t)3 * BH
                                      : a.h0dping + (size_t)((td + 1) & 1) * BH;
            if (td == 0)
                cell_body(bt, nt, smem, hp, hp, a.dwh0, a.dwh0, 8,
                          a.dbih0, a.dbhh0, 2, a.x + (size_t)255 * F, T * F,
                          a.dWih0, nullptr, a.c0, a.h0dping);
            else
                cell_body(bt, nt, smem, hp, hp, a.dwh0, a.dwh0, 8,
                          a.dbih0, a.dbhh0, 3, nullptr, 0,
                          a.dWih0, pred_s, a.c0, a.h0dping + (size_t)(td & 1) * BH);
            __syncthreads();
            if (threadIdx.x == 0)
                __hip_atomic_fetch_add(a.cnt0d + td * 8 + bt, 1,
                                       __ATOMIC_RELEASE, __HIP_MEMORY_SCOPE_AGENT);
        }
    } else {
        const int idx = bid - 256;
        const int bt = idx >> 5, nt = idx & 31;
        // ---- encoder layer1: h1(t) = cell([h0(t)|h1(t-1)]) ----
        for (int t = 0; t < T; ++t) {
            waitcnt_eq(a.cnt0 + t * 8 + bt, 32);                     // h0(t) rows ready
            if (t >= 1) waitcnt_eq(a.cnt1 + (t - 1) * 8 + bt, 32);   // h1(t-1) + self-group
            const f16* a0 = a.h0ring + (size_t)(t & 3) * BH;
            const f16* a1 = a.h1ping + (size_t)((t + 1) & 1) * BH;
            cell_body(bt, nt, smem, a0, a1, a.wih1, a.whh1, (t == 0) ? 8 : 16,
                      a.ebih1, a.ebhh1, 0, nullptr, 0, nullptr, nullptr,
                      a.c1, a.h1ping + (size_t)(t & 1) * BH);
            __syncthreads();
            if (threadIdx.x == 0) {
                __hip_atomic_fetch_add(a.cnt1 + t * 8 + bt, 1,
                                       __ATOMIC_RELEASE, __HIP_MEMORY_SCOPE_AGENT);
                __hip_atomic_fetch_add(a.cons0 + t * 8 + bt, 1,
                                       __ATOMIC_RELAXED, __HIP_MEMORY_SCOPE_AGENT);
            }
        }
        // ---- decoder layer1 ----
        for (int td = 0; td < HOR; ++td) {
            waitcnt_eq(a.cnt0d + td * 8 + bt, 32);                   // h0d(td) ready
            const f16* a1;
            if (td == 0) {
                waitcnt_eq(a.cnt1 + 255 * 8 + bt, 32);               // enc h1 final (self-group)
                a1 = a.h1ping + BH;                                  // h1(255) slot 1
            } else {
                waitcnt_eq(a.cnt1d + (td - 1) * 8 + bt, 32);         // h1d(td-1) full rows
                a1 = a.h1dping + (size_t)((td + 1) & 1) * BH;
            }
            cell_body(bt, nt, smem, a.h0dping + (size_t)(td & 1) * BH, a1,
                      a.dwih1, a.dwhh1, 16, a.dbih1, a.dbhh1,
                      0, nullptr, 0, nullptr, nullptr,
                      a.c1, a.h1dping + (size_t)(td & 1) * BH);
            __syncthreads();
            if (threadIdx.x == 0)
                __hip_atomic_fetch_add(a.cnt1d + td * 8 + bt, 1,
                                       __ATOMIC_RELEASE, __HIP_MEMORY_SCOPE_AGENT);
        }
    }
}

// ---------------------------------------------------------------------------
extern "C" void kernel_launch(void* const* d_in, const int* in_sizes, int n_in,
                              void* d_out, int out_size, void* d_ws, size_t ws_size,
                              hipStream_t stream)
{
    const float* x     = (const float*)d_in[0];
    const float* eWih0 = (const float*)d_in[1];
    const float* eWhh0 = (const float*)d_in[2];
    const float* ebih0 = (const float*)d_in[3];
    const float* ebhh0 = (const float*)d_in[4];
    const float* eWih1 = (const float*)d_in[5];
    const float* eWhh1 = (const float*)d_in[6];
    const float* ebih1 = (const float*)d_in[7];
    const float* ebhh1 = (const float*)d_in[8];
    const float* dWih0 = (const float*)d_in[9];
    const float* dWhh0 = (const float*)d_in[10];
    const float* dbih0 = (const float*)d_in[11];
    const float* dbhh0 = (const float*)d_in[12];
    const float* dWih1 = (const float*)d_in[13];
    const float* dWhh1 = (const float*)d_in[14];
    const float* dbih1 = (const float*)d_in[15];
    const float* dbhh1 = (const float*)d_in[16];
    const float* outW  = (const float*)d_in[17];
    const float* outb  = (const float*)d_in[18];

    const size_t WSZ = (size_t)4 * H * H;   // halfs per converted weight
    const size_t BH  = (size_t)B * H;

    char* wsb = (char*)d_ws;
    size_t off = 0;
    f16* wh[6];
    for (int i = 0; i < 6; ++i) { wh[i] = (f16*)(wsb + off); off += WSZ * sizeof(f16); }
    f16* h0ring  = (f16*)(wsb + off); off += 4 * BH * sizeof(f16);
    f16* h1ping  = (f16*)(wsb + off); off += 2 * BH * sizeof(f16);
    f16* h0dping = (f16*)(wsb + off); off += 2 * BH * sizeof(f16);
    f16* h1dping = (f16*)(wsb + off); off += 2 * BH * sizeof(f16);
    float* c0    = (float*)(wsb + off); off += BH * sizeof(float);
    float* c1    = (float*)(wsb + off); off += BH * sizeof(float);
    int* cnt0    = (int*)(wsb + off);
    size_t coff  = off;
    off += 256 * 8 * sizeof(int);
    int* cnt1    = (int*)(wsb + off); off += 256 * 8 * sizeof(int);
    int* cons0   = (int*)(wsb + off); off += 256 * 8 * sizeof(int);
    int* cnt0d   = (int*)(wsb + off); off += HOR * 8 * sizeof(int);
    int* cnt1d   = (int*)(wsb + off); off += HOR * 8 * sizeof(int);
    size_t cbytes = off - coff;

    // fp16 weight conversion (permuted layout) + state init, every call
    wconv_k<<<dim3(512, 6), 256, 0, stream>>>(eWhh0, wh[0], eWih1, wh[1], eWhh1, wh[2],
                                              dWhh0, wh[3], dWih1, wh[4], dWhh1, wh[5]);
    hipMemsetAsync(c0, 0, BH * sizeof(float), stream);
    hipMemsetAsync(c1, 0, BH * sizeof(float), stream);
    hipMemsetAsync((char*)wsb + coff, 0, cbytes, stream);

    PArgs a;
    a.wh0 = wh[0]; a.wih1 = wh[1]; a.whh1 = wh[2];
    a.dwh0 = wh[3]; a.dwih1 = wh[4]; a.dwhh1 = wh[5];
    a.x = x;
    a.ebih0 = ebih0; a.ebhh0 = ebhh0; a.ebih1 = ebih1; a.ebhh1 = ebhh1;
    a.dbih0 = dbih0; a.dbhh0 = dbhh0; a.dbih1 = dbih1; a.dbhh1 = dbhh1;
    a.eWih0 = eWih0; a.dWih0 = dWih0; a.outW = outW; a.outb = outb;
    a.h0ring = h0ring; a.h1ping = h1ping; a.h0dping = h0dping; a.h1dping = h1dping;
    a.c0 = c0; a.c1 = c1; a.dout = (float*)d_out;
    a.cnt0 = cnt0; a.cnt1 = cnt1; a.cons0 = cons0; a.cnt0d = cnt0d; a.cnt1d = cnt1d;

    persist_k<<<dim3(512), dim3(256), 0, stream>>>(a);
}

// Round 5
// 8835.828 us; speedup vs baseline: 1.4312x; 1.4312x over previous
//
#include <hip/hip_runtime.h>
#include <math.h>

constexpr int H   = 512;
constexpr int B   = 512;
constexpr int T   = 256;
constexpr int F   = 8;
constexpr int HOR = 24;

typedef _Float16 f16;
typedef _Float16 f16x8 __attribute__((ext_vector_type(8)));
typedef float    f32x4 __attribute__((ext_vector_type(4)));

__device__ __forceinline__ float sigm(float x) { return 1.0f / (1.0f + expf(-x)); }

// ---------------------------------------------------------------------------
// Weight convert: fp32 [4H][H] gate-major rows (row = g*H + jh) -> fp16
// [2048][512] permuted rows n' = jh*4 + g. grid (512, 6).
__global__ __launch_bounds__(256)
void wconv_k(const float* __restrict__ s0, f16* __restrict__ d0,
             const float* __restrict__ s1, f16* __restrict__ d1,
             const float* __restrict__ s2, f16* __restrict__ d2,
             const float* __restrict__ s3, f16* __restrict__ d3,
             const float* __restrict__ s4, f16* __restrict__ d4,
             const float* __restrict__ s5, f16* __restrict__ d5)
{
    const float* src; f16* dst;
    switch (blockIdx.y) {
        case 0:  src = s0; dst = d0; break;
        case 1:  src = s1; dst = d1; break;
        case 2:  src = s2; dst = d2; break;
        case 3:  src = s3; dst = d3; break;
        case 4:  src = s4; dst = d4; break;
        default: src = s5; dst = d5; break;
    }
    int idx = (blockIdx.x * 256 + threadIdx.x) * 8;
    int np  = idx >> 9;
    int k   = idx & 511;
    int jh  = np >> 2, g = np & 3;
    const float* sp = src + (size_t)(g * H + jh) * H + k;
    f16 tmp[8];
    #pragma unroll
    for (int j = 0; j < 8; ++j) tmp[j] = (f16)sp[j];
    *(f16x8*)(dst + idx) = *(const f16x8*)tmp;
}

// ---------------------------------------------------------------------------
// Flat-flag sync: 32 producer blocks each own one epoch word (no RMW, no
// shared-line contention). Consumer: wave0 lanes 0-31 poll the 32 words with
// one coalesced 128B load, exit when all >= target, then acquire-load (L1/L2
// invalidate for cross-XCD freshness), barrier.
__device__ __forceinline__ void wait_group(int* f, int target)
{
    if (threadIdx.x < 64) {
        const int l = threadIdx.x & 63;
        bool ok;
        do {
            int v = target;
            if (l < 32)
                v = __hip_atomic_load(f + l, __ATOMIC_RELAXED, __HIP_MEMORY_SCOPE_AGENT);
            ok = __all(v >= target);
            if (!ok) __builtin_amdgcn_s_sleep(2);
        } while (!ok);
        if (l < 32)
            (void)__hip_atomic_load(f + l, __ATOMIC_ACQUIRE, __HIP_MEMORY_SCOPE_AGENT);
    }
    __syncthreads();
}

// ---------------------------------------------------------------------------
struct Chunk { f16x8 a0, a1, w0, w1; };

// A rows: kt<8 from A0, kt>=8 from A1 (K up to 1024). BM=64 fixed.
__device__ __forceinline__ Chunk load_chunk(int kt,
    const f16* __restrict__ A0, const f16* __restrict__ A1,
    const f16* __restrict__ W0, const f16* __restrict__ W1,
    int b0, int n0, int srow, int sch)
{
    const f16* Ap = (kt < 8) ? A0 : A1;
    const f16* Wp = (kt < 8) ? W0 : W1;
    const int  ko = ((kt < 8) ? kt : kt - 8) * 64;
    Chunk c;
    const f16* ap = Ap + (size_t)(b0 + srow) * H + ko + sch * 16;
    c.a0 = *(const f16x8*)ap;
    c.a1 = *(const f16x8*)(ap + 8);
    const f16* wp = Wp + (size_t)(n0 + srow) * H + ko + sch * 16;
    c.w0 = *(const f16x8*)wp;
    c.w1 = *(const f16x8*)(wp + 8);
    return c;
}

// Fused LSTM cell tile, 64 b-rows x 64 n', K = nkt*64 (nkt = 0, 8 or 16).
// xmode: 0 none; 1 enc0 x-path (F=8 fp32); 2 scalar from xptr[b*xstride];
//        3 scalar from LDS pred_s[bl].
__device__ void cell_body(int bt, int nt, char* smem,
    const f16* __restrict__ A0, const f16* __restrict__ A1,
    const f16* __restrict__ W0, const f16* __restrict__ W1, int nkt,
    const float* __restrict__ bih, const float* __restrict__ bhh,
    int xmode, const float* __restrict__ xptr, int xstride,
    const float* __restrict__ xw, const float* __restrict__ pred_s,
    float* __restrict__ cst, f16* __restrict__ hout)
{
    constexpr int ABUF = 64 * 72;                  // halfs per buffer slot
    f16*   As = (f16*)smem;                        // [2][64][72]
    f16*   Ws = (f16*)smem + 2 * ABUF;             // [2][64][72]
    float* zs = (float*)smem;                      // overlay after K-loop

    const int tid  = threadIdx.x;
    const int lane = tid & 63;
    const int wv   = tid >> 6;
    const int wm   = wv & 1;
    const int wn   = wv >> 1;
    const int r    = lane & 15;
    const int g4   = lane >> 4;
    const int b0   = bt * 64;
    const int n0   = nt * 64;
    const int jh0  = nt * 16;
    const int srow = tid >> 2, sch = tid & 3;

    f32x4 acc[2][2] = {};

    Chunk cur = {};
    if (nkt > 0) cur = load_chunk(0, A0, A1, W0, W1, b0, n0, srow, sch);

    for (int kt = 0; kt < nkt; ++kt) {
        const int p = kt & 1;
        f16* Ab = As + p * ABUF;
        f16* Wb = Ws + p * ABUF;
        *(f16x8*)(Ab + srow * 72 + sch * 16)     = cur.a0;
        *(f16x8*)(Ab + srow * 72 + sch * 16 + 8) = cur.a1;
        *(f16x8*)(Wb + srow * 72 + sch * 16)     = cur.w0;
        *(f16x8*)(Wb + srow * 72 + sch * 16 + 8) = cur.w1;
        __syncthreads();

        Chunk nxt = cur;
        if (kt + 1 < nkt)
            nxt = load_chunk(kt + 1, A0, A1, W0, W1, b0, n0, srow, sch);

        #pragma unroll
        for (int sub = 0; sub < 2; ++sub) {
            f16x8 bf0 = *(const f16x8*)(Wb + (wn * 32 + r)      * 72 + sub * 32 + g4 * 8);
            f16x8 bf1 = *(const f16x8*)(Wb + (wn * 32 + 16 + r) * 72 + sub * 32 + g4 * 8);
            f16x8 af0 = *(const f16x8*)(Ab + (wm * 32 + r)      * 72 + sub * 32 + g4 * 8);
            f16x8 af1 = *(const f16x8*)(Ab + (wm * 32 + 16 + r) * 72 + sub * 32 + g4 * 8);
            acc[0][0] = __builtin_amdgcn_mfma_f32_16x16x32_f16(af0, bf0, acc[0][0], 0, 0, 0);
            acc[0][1] = __builtin_amdgcn_mfma_f32_16x16x32_f16(af0, bf1, acc[0][1], 0, 0, 0);
            acc[1][0] = __builtin_amdgcn_mfma_f32_16x16x32_f16(af1, bf0, acc[1][0], 0, 0, 0);
            acc[1][1] = __builtin_amdgcn_mfma_f32_16x16x32_f16(af1, bf1, acc[1][1], 0, 0, 0);
        }
        cur = nxt;
    }

    __syncthreads();   // last frag reads drained before zs overlay
    #pragma unroll
    for (int fm = 0; fm < 2; ++fm)
        #pragma unroll
        for (int fn = 0; fn < 2; ++fn)
            #pragma unroll
            for (int j = 0; j < 4; ++j)
                zs[(wm * 32 + fm * 16 + g4 * 4 + j) * 68 +
                   (wn * 32 + fn * 16 + r)] = acc[fm][fn][j];
    __syncthreads();

    // epilogue: thread -> (4 b-rows, 1 jh); gates = 4 consecutive n'.
    const int jl = tid & 15;
    const int bq = tid >> 4;
    const int jh = jh0 + jl;

    float bsum[4];
    #pragma unroll
    for (int g = 0; g < 4; ++g) bsum[g] = bih[g * H + jh] + bhh[g * H + jh];

    #pragma unroll
    for (int bb = 0; bb < 4; ++bb) {
        const int bl = bq * 4 + bb;
        const int b  = b0 + bl;
        float4 z = *(const float4*)(zs + bl * 68 + jl * 4);
        float zi = z.x + bsum[0];
        float zf = z.y + bsum[1];
        float zg = z.z + bsum[2];
        float zo = z.w + bsum[3];
        if (xmode == 1) {
            const float* xr = xptr + (size_t)b * xstride;
            #pragma unroll
            for (int k = 0; k < F; ++k) {
                float xv = xr[k];
                zi += xv * xw[(0 * H + jh) * F + k];
                zf += xv * xw[(1 * H + jh) * F + k];
                zg += xv * xw[(2 * H + jh) * F + k];
                zo += xv * xw[(3 * H + jh) * F + k];
            }
        } else if (xmode == 2 || xmode == 3) {
            float xv = (xmode == 2) ? xptr[(size_t)b * xstride] : pred_s[bl];
            zi += xv * xw[0 * H + jh];
            zf += xv * xw[1 * H + jh];
            zg += xv * xw[2 * H + jh];
            zo += xv * xw[3 * H + jh];
        }
        size_t idx = (size_t)b * H + jh;
        float cold = cst[idx];
        float cn = sigm(zf) * cold + sigm(zi) * tanhf(zg);
        cst[idx] = cn;
        hout[idx] = (f16)(sigm(zo) * tanhf(cn));
    }
}

// ---------------------------------------------------------------------------
// pred for 64 rows of this bt: pred_s[row] = h1row . outW + outb.
// All 32 nt blocks compute redundantly; only nt==0 writes d_out[., oidx].
__device__ void compute_pred(int bt, int nt, const f16* __restrict__ h1src,
                             const float* __restrict__ outW,
                             const float* __restrict__ outb,
                             float* pred_s, float* __restrict__ dout, int oidx)
{
    const int row = threadIdx.x >> 2;
    const int q   = threadIdx.x & 3;
    const int b   = bt * 64 + row;
    const f16x8* hv = (const f16x8*)(h1src + (size_t)b * H + q * 128);
    const float* wr = outW + q * 128;
    float s = 0.f;
    #pragma unroll
    for (int k8 = 0; k8 < 16; ++k8) {
        f16x8 h8 = hv[k8];
        #pragma unroll
        for (int j = 0; j < 8; ++j) s += (float)h8[j] * wr[k8 * 8 + j];
    }
    s += __shfl_down(s, 2);
    s += __shfl_down(s, 1);
    if (q == 0) {
        float p = s + outb[0];
        pred_s[row] = p;
        if (nt == 0) dout[(size_t)b * HOR + oidx] = p;
    }
    __syncthreads();
}

// ---------------------------------------------------------------------------
struct PArgs {
    const f16 *wh0, *wih1, *whh1, *dwh0, *dwih1, *dwhh1;
    const float *x;
    const float *ebih0, *ebhh0, *ebih1, *ebhh1;
    const float *dbih0, *dbhh0, *dbih1, *dbhh1;
    const float *eWih0, *dWih0, *outW, *outb;
    f16 *h0ring, *h1ping, *h0dping, *h1dping;
    float *c0, *c1, *dout;
    int *f0, *f1, *fc0, *f0d, *f1d;   // epoch flags, [8 bt][32 nt] each
};

// Persistent kernel: 512 blocks (2/CU: 37.1KB LDS, 256 thr, launch_bounds(256,2)).
// bt = bid&7, role = (bid>>3)&1, nt = bid>>4  =>  all 64 blocks of a bt-group
// land on one XCD under round-robin bid%8 mapping (locality heuristic only;
// correctness comes from agent-scope release/acquire).
__global__ __launch_bounds__(256, 2)
void persist_k(PArgs a)
{
    __shared__ __align__(16) char smem[37120];
    float* pred_s = (float*)(smem + 36864);
    const size_t BH = (size_t)B * H;
    const int bid  = blockIdx.x;
    const int bt   = bid & 7;
    const int role = (bid >> 3) & 1;
    const int nt   = bid >> 4;
    int* const myf0  = a.f0  + bt * 32;
    int* const myf1  = a.f1  + bt * 32;
    int* const myfc0 = a.fc0 + bt * 32;
    int* const myf0d = a.f0d + bt * 32;
    int* const myf1d = a.f1d + bt * 32;

    if (role == 0) {
        // ---- encoder layer0: h0(t) = cell(x(t), h0(t-1)) ----
        for (int t = 0; t < T; ++t) {
            if (t >= 1) wait_group(myf0, t);        // h0(t-1) ready (all 32 cols)
            if (t >= 4) wait_group(myfc0, t - 3);   // ring slot consumed by layer1
            const f16* hp = a.h0ring + (size_t)((t + 3) & 3) * BH;
            cell_body(bt, nt, smem, hp, hp, a.wh0, a.wh0, (t == 0) ? 0 : 8,
                      a.ebih0, a.ebhh0, 1, a.x + (size_t)t * F, T * F, a.eWih0,
                      nullptr, a.c0, a.h0ring + (size_t)(t & 3) * BH);
            __syncthreads();
            if (threadIdx.x == 0)
                __hip_atomic_store(myf0 + nt, t + 1,
                                   __ATOMIC_RELEASE, __HIP_MEMORY_SCOPE_AGENT);
        }
        // ---- decoder layer0 (+ pred head) ----
        for (int td = 0; td <= HOR; ++td) {
            if (td == 0) {
                wait_group(myf0, T);                // own group enc done
            } else {
                wait_group(myf1d, td);              // h1d(td-1) ready
                compute_pred(bt, nt, a.h1dping + (size_t)((td + 1) & 1) * BH,
                             a.outW, a.outb, pred_s, a.dout, td - 1);
            }
            if (td == HOR) break;
            if (td >= 1) wait_group(myf0d, td);     // h0d(td-1) ready
            const f16* hp = (td == 0) ? a.h0ring + (size_t)3 * BH
                                      : a.h0dping + (size_t)((td + 1) & 1) * BH;
            if (td == 0)
                cell_body(bt, nt, smem, hp, hp, a.dwh0, a.dwh0, 8,
                          a.dbih0, a.dbhh0, 2, a.x + (size_t)(T - 1) * F, T * F,
                          a.dWih0, nullptr, a.c0, a.h0dping);
            else
                cell_body(bt, nt, smem, hp, hp, a.dwh0, a.dwh0, 8,
                          a.dbih0, a.dbhh0, 3, nullptr, 0,
                          a.dWih0, pred_s, a.c0, a.h0dping + (size_t)(td & 1) * BH);
            __syncthreads();
            if (threadIdx.x == 0)
                __hip_atomic_store(myf0d + nt, td + 1,
                                   __ATOMIC_RELEASE, __HIP_MEMORY_SCOPE_AGENT);
        }
    } else {
        // ---- encoder layer1: h1(t) = cell([h0(t)|h1(t-1)]) ----
        for (int t = 0; t < T; ++t) {
            wait_group(myf0, t + 1);                // h0(t) ready
            if (t >= 1) wait_group(myf1, t);        // h1(t-1) ready
            const f16* a0 = a.h0ring + (size_t)(t & 3) * BH;
            const f16* a1 = a.h1ping + (size_t)((t + 1) & 1) * BH;
            cell_body(bt, nt, smem, a0, a1, a.wih1, a.whh1, (t == 0) ? 8 : 16,
                      a.ebih1, a.ebhh1, 0, nullptr, 0, nullptr, nullptr,
                      a.c1, a.h1ping + (size_t)(t & 1) * BH);
            __syncthreads();
            if (threadIdx.x == 0) {
                __hip_atomic_store(myf1 + nt, t + 1,
                                   __ATOMIC_RELEASE, __HIP_MEMORY_SCOPE_AGENT);
                __hip_atomic_store(myfc0 + nt, t + 1,
                                   __ATOMIC_RELAXED, __HIP_MEMORY_SCOPE_AGENT);
            }
        }
        // ---- decoder layer1 ----
        for (int td = 0; td < HOR; ++td) {
            wait_group(myf0d, td + 1);              // h0d(td) ready
            const f16* a1;
            if (td == 0) { wait_group(myf1, T);  a1 = a.h1ping + BH; }
            else         { wait_group(myf1d, td); a1 = a.h1dping + (size_t)((td + 1) & 1) * BH; }
            cell_body(bt, nt, smem, a.h0dping + (size_t)(td & 1) * BH, a1,
                      a.dwih1, a.dwhh1, 16, a.dbih1, a.dbhh1,
                      0, nullptr, 0, nullptr, nullptr,
                      a.c1, a.h1dping + (size_t)(td & 1) * BH);
            __syncthreads();
            if (threadIdx.x == 0)
                __hip_atomic_store(myf1d + nt, td + 1,
                                   __ATOMIC_RELEASE, __HIP_MEMORY_SCOPE_AGENT);
        }
    }
}

// ---------------------------------------------------------------------------
extern "C" void kernel_launch(void* const* d_in, const int* in_sizes, int n_in,
                              void* d_out, int out_size, void* d_ws, size_t ws_size,
                              hipStream_t stream)
{
    const float* x     = (const float*)d_in[0];
    const float* eWih0 = (const float*)d_in[1];
    const float* eWhh0 = (const float*)d_in[2];
    const float* ebih0 = (const float*)d_in[3];
    const float* ebhh0 = (const float*)d_in[4];
    const float* eWih1 = (const float*)d_in[5];
    const float* eWhh1 = (const float*)d_in[6];
    const float* ebih1 = (const float*)d_in[7];
    const float* ebhh1 = (const float*)d_in[8];
    const float* dWih0 = (const float*)d_in[9];
    const float* dWhh0 = (const float*)d_in[10];
    const float* dbih0 = (const float*)d_in[11];
    const float* dbhh0 = (const float*)d_in[12];
    const float* dWih1 = (const float*)d_in[13];
    const float* dWhh1 = (const float*)d_in[14];
    const float* dbih1 = (const float*)d_in[15];
    const float* dbhh1 = (const float*)d_in[16];
    const float* outW  = (const float*)d_in[17];
    const float* outb  = (const float*)d_in[18];

    const size_t WSZ = (size_t)4 * H * H;   // halfs per converted weight
    const size_t BH  = (size_t)B * H;

    char* wsb = (char*)d_ws;
    size_t off = 0;
    f16* wh[6];
    for (int i = 0; i < 6; ++i) { wh[i] = (f16*)(wsb + off); off += WSZ * sizeof(f16); }
    f16* h0ring  = (f16*)(wsb + off); off += 4 * BH * sizeof(f16);
    f16* h1ping  = (f16*)(wsb + off); off += 2 * BH * sizeof(f16);
    f16* h0dping = (f16*)(wsb + off); off += 2 * BH * sizeof(f16);
    f16* h1dping = (f16*)(wsb + off); off += 2 * BH * sizeof(f16);
    float* c0    = (float*)(wsb + off); off += BH * sizeof(float);
    float* c1    = (float*)(wsb + off); off += BH * sizeof(float);
    size_t coff  = off;
    int* f0      = (int*)(wsb + off); off += 8 * 32 * sizeof(int);
    int* f1      = (int*)(wsb + off); off += 8 * 32 * sizeof(int);
    int* fc0     = (int*)(wsb + off); off += 8 * 32 * sizeof(int);
    int* f0d     = (int*)(wsb + off); off += 8 * 32 * sizeof(int);
    int* f1d     = (int*)(wsb + off); off += 8 * 32 * sizeof(int);
    size_t cbytes = off - coff;

    // fp16 weight conversion (permuted layout) + state/flag init, every call
    wconv_k<<<dim3(512, 6), 256, 0, stream>>>(eWhh0, wh[0], eWih1, wh[1], eWhh1, wh[2],
                                              dWhh0, wh[3], dWih1, wh[4], dWhh1, wh[5]);
    hipMemsetAsync(c0, 0, BH * sizeof(float), stream);
    hipMemsetAsync(c1, 0, BH * sizeof(float), stream);
    hipMemsetAsync((char*)wsb + coff, 0, cbytes, stream);

    PArgs a;
    a.wh0 = wh[0]; a.wih1 = wh[1]; a.whh1 = wh[2];
    a.dwh0 = wh[3]; a.dwih1 = wh[4]; a.dwhh1 = wh[5];
    a.x = x;
    a.ebih0 = ebih0; a.ebhh0 = ebhh0; a.ebih1 = ebih1; a.ebhh1 = ebhh1;
    a.dbih0 = dbih0; a.dbhh0 = dbhh0; a.dbih1 = dbih1; a.dbhh1 = dbhh1;
    a.eWih0 = eWih0; a.dWih0 = dWih0; a.outW = outW; a.outb = outb;
    a.h0ring = h0ring; a.h1ping = h1ping; a.h0dping = h0dping; a.h1dping = h1dping;
    a.c0 = c0; a.c1 = c1; a.dout = (float*)d_out;
    a.f0 = f0; a.f1 = f1; a.fc0 = fc0; a.f0d = f0d; a.f1d = f1d;

    persist_k<<<dim3(512), dim3(256), 0, stream>>>(a);
}

// Round 6
// 5960.569 us; speedup vs baseline: 2.1216x; 1.4824x over previous
//
#include <hip/hip_runtime.h>
#include <math.h>

constexpr int H   = 512;
constexpr int B   = 512;
constexpr int T   = 256;
constexpr int F   = 8;
constexpr int HOR = 24;

typedef _Float16 f16;
typedef _Float16 f16x8 __attribute__((ext_vector_type(8)));
typedef float    f32x4 __attribute__((ext_vector_type(4)));

__device__ __forceinline__ float sigm(float x) { return 1.0f / (1.0f + expf(-x)); }

// ---------------------------------------------------------------------------
// LLC-coherent (cross-XCD) access path: sc0 sc1 bypasses L1/L2, data lives in
// the shared Infinity Cache. Used for ALL h-tile and flag traffic. Weights /
// x / biases / c stay on the normal cached path (L2 never invalidated).
// 16 strided 16B loads: two 16B chunks per 128B K-chunk (offs k*128+{0,16}).
#define LLC_LOAD16S(base, r) \
  asm volatile( \
    "global_load_dwordx4 %0,  %16, off sc0 sc1\n\t" \
    "global_load_dwordx4 %1,  %16, off offset:16 sc0 sc1\n\t" \
    "global_load_dwordx4 %2,  %16, off offset:128 sc0 sc1\n\t" \
    "global_load_dwordx4 %3,  %16, off offset:144 sc0 sc1\n\t" \
    "global_load_dwordx4 %4,  %16, off offset:256 sc0 sc1\n\t" \
    "global_load_dwordx4 %5,  %16, off offset:272 sc0 sc1\n\t" \
    "global_load_dwordx4 %6,  %16, off offset:384 sc0 sc1\n\t" \
    "global_load_dwordx4 %7,  %16, off offset:400 sc0 sc1\n\t" \
    "global_load_dwordx4 %8,  %16, off offset:512 sc0 sc1\n\t" \
    "global_load_dwordx4 %9,  %16, off offset:528 sc0 sc1\n\t" \
    "global_load_dwordx4 %10, %16, off offset:640 sc0 sc1\n\t" \
    "global_load_dwordx4 %11, %16, off offset:656 sc0 sc1\n\t" \
    "global_load_dwordx4 %12, %16, off offset:768 sc0 sc1\n\t" \
    "global_load_dwordx4 %13, %16, off offset:784 sc0 sc1\n\t" \
    "global_load_dwordx4 %14, %16, off offset:896 sc0 sc1\n\t" \
    "global_load_dwordx4 %15, %16, off offset:912 sc0 sc1" \
    : "=v"(r[0]), "=v"(r[1]), "=v"(r[2]), "=v"(r[3]), \
      "=v"(r[4]), "=v"(r[5]), "=v"(r[6]), "=v"(r[7]), \
      "=v"(r[8]), "=v"(r[9]), "=v"(r[10]), "=v"(r[11]), \
      "=v"(r[12]), "=v"(r[13]), "=v"(r[14]), "=v"(r[15]) \
    : "v"(base))

// 16 contiguous 16B loads (256B run) for the pred head.
#define LLC_LOAD16C(base, r) \
  asm volatile( \
    "global_load_dwordx4 %0,  %16, off sc0 sc1\n\t" \
    "global_load_dwordx4 %1,  %16, off offset:16 sc0 sc1\n\t" \
    "global_load_dwordx4 %2,  %16, off offset:32 sc0 sc1\n\t" \
    "global_load_dwordx4 %3,  %16, off offset:48 sc0 sc1\n\t" \
    "global_load_dwordx4 %4,  %16, off offset:64 sc0 sc1\n\t" \
    "global_load_dwordx4 %5,  %16, off offset:80 sc0 sc1\n\t" \
    "global_load_dwordx4 %6,  %16, off offset:96 sc0 sc1\n\t" \
    "global_load_dwordx4 %7,  %16, off offset:112 sc0 sc1\n\t" \
    "global_load_dwordx4 %8,  %16, off offset:128 sc0 sc1\n\t" \
    "global_load_dwordx4 %9,  %16, off offset:144 sc0 sc1\n\t" \
    "global_load_dwordx4 %10, %16, off offset:160 sc0 sc1\n\t" \
    "global_load_dwordx4 %11, %16, off offset:176 sc0 sc1\n\t" \
    "global_load_dwordx4 %12, %16, off offset:192 sc0 sc1\n\t" \
    "global_load_dwordx4 %13, %16, off offset:208 sc0 sc1\n\t" \
    "global_load_dwordx4 %14, %16, off offset:224 sc0 sc1\n\t" \
    "global_load_dwordx4 %15, %16, off offset:240 sc0 sc1" \
    : "=v"(r[0]), "=v"(r[1]), "=v"(r[2]), "=v"(r[3]), \
      "=v"(r[4]), "=v"(r[5]), "=v"(r[6]), "=v"(r[7]), \
      "=v"(r[8]), "=v"(r[9]), "=v"(r[10]), "=v"(r[11]), \
      "=v"(r[12]), "=v"(r[13]), "=v"(r[14]), "=v"(r[15]) \
    : "v"(base))

// Drain vmcnt and ORDER all subsequent uses of r[] after it ("+v" ties).
#define VWAIT16(r) \
  asm volatile("s_waitcnt vmcnt(0)" \
    : "+v"(r[0]), "+v"(r[1]), "+v"(r[2]), "+v"(r[3]), \
      "+v"(r[4]), "+v"(r[5]), "+v"(r[6]), "+v"(r[7]), \
      "+v"(r[8]), "+v"(r[9]), "+v"(r[10]), "+v"(r[11]), \
      "+v"(r[12]), "+v"(r[13]), "+v"(r[14]), "+v"(r[15]) :: "memory")

// h-element write-through store (2B).
#define LLC_STORE_SHORT(p, v) \
  asm volatile("global_store_short %0, %1, off sc0 sc1" :: "v"(p), "v"(v) : "memory")

// Release-ish flag store: all prior stores (h, sc0sc1 write-through) reach the
// LLC before the flag becomes visible there. No cache-maintenance ops.
#define FLAG_STORE(p, v) \
  asm volatile("s_waitcnt vmcnt(0)\n\t" \
               "global_store_dword %0, %1, off sc0 sc1" :: "v"(p), "v"(v) : "memory")
#define FLAG_STORE_NW(p, v) \
  asm volatile("global_store_dword %0, %1, off sc0 sc1" :: "v"(p), "v"(v) : "memory")

// ---------------------------------------------------------------------------
// Weight convert: fp32 [4H][H] gate-major rows (row = g*H + jh) -> fp16
// [2048][512] permuted rows n' = jh*4 + g. grid (512, 6).
__global__ __launch_bounds__(256)
void wconv_k(const float* __restrict__ s0, f16* __restrict__ d0,
             const float* __restrict__ s1, f16* __restrict__ d1,
             const float* __restrict__ s2, f16* __restrict__ d2,
             const float* __restrict__ s3, f16* __restrict__ d3,
             const float* __restrict__ s4, f16* __restrict__ d4,
             const float* __restrict__ s5, f16* __restrict__ d5)
{
    const float* src; f16* dst;
    switch (blockIdx.y) {
        case 0:  src = s0; dst = d0; break;
        case 1:  src = s1; dst = d1; break;
        case 2:  src = s2; dst = d2; break;
        case 3:  src = s3; dst = d3; break;
        case 4:  src = s4; dst = d4; break;
        default: src = s5; dst = d5; break;
    }
    int idx = (blockIdx.x * 256 + threadIdx.x) * 8;
    int np  = idx >> 9;
    int k   = idx & 511;
    int jh  = np >> 2, g = np & 3;
    const float* sp = src + (size_t)(g * H + jh) * H + k;
    f16 tmp[8];
    #pragma unroll
    for (int j = 0; j < 8; ++j) tmp[j] = (f16)sp[j];
    *(f16x8*)(dst + idx) = *(const f16x8*)tmp;
}

// ---------------------------------------------------------------------------
// Poll 32 per-producer epoch flags with LLC loads (no fences, no L2 inv).
__device__ __forceinline__ void wait_group(const int* f, int target)
{
    if (threadIdx.x < 64) {
        const int* p = f + (threadIdx.x & 31);
        bool ok;
        do {
            int v;
            asm volatile("global_load_dword %0, %1, off sc0 sc1\n\t"
                         "s_waitcnt vmcnt(0)"
                         : "=v"(v) : "v"(p) : "memory");
            ok = __all(v >= target);
            if (!ok) __builtin_amdgcn_s_sleep(1);
        } while (!ok);
    }
    __syncthreads();
}

// ---------------------------------------------------------------------------
struct WChunk { f16x8 w0, w1; };

__device__ __forceinline__ WChunk loadW(int kt, const f16* __restrict__ W0,
                                        const f16* __restrict__ W1,
                                        int n0, int srow, int sch)
{
    const f16* Wp = (kt < 8) ? W0 : W1;
    const int  ko = ((kt < 8) ? kt : kt - 8) * 64;
    const f16* wp = Wp + (size_t)(n0 + srow) * H + ko + sch * 16;
    WChunk c;
    c.w0 = *(const f16x8*)wp;
    c.w1 = *(const f16x8*)(wp + 8);
    return c;
}

// Fused LSTM cell tile, 64 b-rows x 64 n', K = NKT*64 (NKT = 0, 8 or 16).
// A (h state) read via LLC loads prefetched to registers; W via cached loads
// (double-buffered LDS, compiler-pipelined). xmode: 0 none; 1 enc0 F=8 fp32
// x-path; 2 scalar from xptr[b*xstride]; 3 scalar from LDS pred_s[bl].
template<int NKT>
__device__ __forceinline__ void cell_body(int bt, int nt, char* smem,
    const f16* __restrict__ A0, const f16* __restrict__ A1,
    const f16* __restrict__ W0, const f16* __restrict__ W1,
    const float* __restrict__ bih, const float* __restrict__ bhh,
    int xmode, const float* __restrict__ xptr, int xstride,
    const float* __restrict__ xw, const float* __restrict__ pred_s,
    float* __restrict__ cst, f16* __restrict__ hout)
{
    constexpr int ABUF = 64 * 72;                  // halfs per buffer slot
    f16*   As = (f16*)smem;                        // [2][64][72]
    f16*   Ws = (f16*)smem + 2 * ABUF;             // [2][64][72]
    float* zs = (float*)smem;                      // overlay after K-loop

    const int tid  = threadIdx.x;
    const int lane = tid & 63;
    const int wv   = tid >> 6;
    const int wm   = wv & 1;
    const int wn   = wv >> 1;
    const int r    = lane & 15;
    const int g4   = lane >> 4;
    const int b0   = bt * 64;
    const int n0   = nt * 64;
    const int jh0  = nt * 16;
    const int srow = tid >> 2, sch = tid & 3;

    f32x4 acc[2][2] = {};

    if constexpr (NKT > 0) {
        f16x8 ar[16];          // K-half 0 (A0), all 16 chunks of this thread's row
        f16x8 br[16];          // K-half 1 (A1), NKT==16 only
        const f16* ap = A0 + (size_t)(b0 + srow) * H + sch * 16;
        LLC_LOAD16S(ap, ar);
        if constexpr (NKT == 16) {
            const f16* bp = A1 + (size_t)(b0 + srow) * H + sch * 16;
            LLC_LOAD16S(bp, br);
        }
        VWAIT16(ar);           // drains all outstanding (incl. br group)

        WChunk wcur = loadW(0, W0, W1, n0, srow, sch);
        #pragma unroll
        for (int kt = 0; kt < NKT; ++kt) {
            if (kt == 8) VWAIT16(br);              // ordering formality (already arrived)
            f16* Ab = As + (kt & 1) * ABUF;
            f16* Wb = Ws + (kt & 1) * ABUF;
            f16x8 a0v = (kt < 8) ? ar[kt * 2]     : br[(kt - 8) * 2];
            f16x8 a1v = (kt < 8) ? ar[kt * 2 + 1] : br[(kt - 8) * 2 + 1];
            *(f16x8*)(Ab + srow * 72 + sch * 16)     = a0v;
            *(f16x8*)(Ab + srow * 72 + sch * 16 + 8) = a1v;
            *(f16x8*)(Wb + srow * 72 + sch * 16)     = wcur.w0;
            *(f16x8*)(Wb + srow * 72 + sch * 16 + 8) = wcur.w1;
            __syncthreads();

            WChunk wnxt = wcur;
            if (kt + 1 < NKT) wnxt = loadW(kt + 1, W0, W1, n0, srow, sch);

            #pragma unroll
            for (int sub = 0; sub < 2; ++sub) {
                f16x8 bf0 = *(const f16x8*)(Wb + (wn * 32 + r)      * 72 + sub * 32 + g4 * 8);
                f16x8 bf1 = *(const f16x8*)(Wb + (wn * 32 + 16 + r) * 72 + sub * 32 + g4 * 8);
                f16x8 af0 = *(const f16x8*)(Ab + (wm * 32 + r)      * 72 + sub * 32 + g4 * 8);
                f16x8 af1 = *(const f16x8*)(Ab + (wm * 32 + 16 + r) * 72 + sub * 32 + g4 * 8);
                acc[0][0] = __builtin_amdgcn_mfma_f32_16x16x32_f16(af0, bf0, acc[0][0], 0, 0, 0);
                acc[0][1] = __builtin_amdgcn_mfma_f32_16x16x32_f16(af0, bf1, acc[0][1], 0, 0, 0);
                acc[1][0] = __builtin_amdgcn_mfma_f32_16x16x32_f16(af1, bf0, acc[1][0], 0, 0, 0);
                acc[1][1] = __builtin_amdgcn_mfma_f32_16x16x32_f16(af1, bf1, acc[1][1], 0, 0, 0);
            }
            wcur = wnxt;
        }
    }

    __syncthreads();   // last frag reads drained before zs overlay
    #pragma unroll
    for (int fm = 0; fm < 2; ++fm)
        #pragma unroll
        for (int fn = 0; fn < 2; ++fn)
            #pragma unroll
            for (int j = 0; j < 4; ++j)
                zs[(wm * 32 + fm * 16 + g4 * 4 + j) * 68 +
                   (wn * 32 + fn * 16 + r)] = acc[fm][fn][j];
    __syncthreads();

    // epilogue: thread -> (4 b-rows, 1 jh); gates = 4 consecutive n'.
    const int jl = tid & 15;
    const int bq = tid >> 4;
    const int jh = jh0 + jl;

    float bsum[4];
    #pragma unroll
    for (int g = 0; g < 4; ++g) bsum[g] = bih[g * H + jh] + bhh[g * H + jh];

    #pragma unroll
    for (int bb = 0; bb < 4; ++bb) {
        const int bl = bq * 4 + bb;
        const int b  = b0 + bl;
        float4 z = *(const float4*)(zs + bl * 68 + jl * 4);
        float zi = z.x + bsum[0];
        float zf = z.y + bsum[1];
        float zg = z.z + bsum[2];
        float zo = z.w + bsum[3];
        if (xmode == 1) {
            const float* xr = xptr + (size_t)b * xstride;
            #pragma unroll
            for (int k = 0; k < F; ++k) {
                float xv = xr[k];
                zi += xv * xw[(0 * H + jh) * F + k];
                zf += xv * xw[(1 * H + jh) * F + k];
                zg += xv * xw[(2 * H + jh) * F + k];
                zo += xv * xw[(3 * H + jh) * F + k];
            }
        } else if (xmode == 2 || xmode == 3) {
            float xv = (xmode == 2) ? xptr[(size_t)b * xstride] : pred_s[bl];
            zi += xv * xw[0 * H + jh];
            zf += xv * xw[1 * H + jh];
            zg += xv * xw[2 * H + jh];
            zo += xv * xw[3 * H + jh];
        }
        size_t idx = (size_t)b * H + jh;
        float cold = cst[idx];                      // c is block-private: cached path
        float cn = sigm(zf) * cold + sigm(zi) * tanhf(zg);
        cst[idx] = cn;
        union { f16 h; unsigned short u; } cv;
        cv.h = (f16)(sigm(zo) * tanhf(cn));
        LLC_STORE_SHORT(hout + idx, (int)cv.u);     // h crosses blocks: LLC path
    }
}

// ---------------------------------------------------------------------------
// pred for 64 rows of this bt: pred_s[row] = h1row . outW + outb.
// All 32 nt blocks compute redundantly; only nt==0 writes d_out[., oidx].
__device__ __forceinline__ void compute_pred(int bt, int nt,
                             const f16* __restrict__ h1src,
                             const float* __restrict__ outW,
                             const float* __restrict__ outb,
                             float* pred_s, float* __restrict__ dout, int oidx)
{
    const int row = threadIdx.x >> 2;
    const int q   = threadIdx.x & 3;
    const int b   = bt * 64 + row;
    f16x8 hr[16];
    const f16* hp = h1src + (size_t)b * H + q * 128;
    LLC_LOAD16C(hp, hr);
    VWAIT16(hr);
    float s = 0.f;
    #pragma unroll
    for (int k8 = 0; k8 < 16; ++k8) {
        const float* wr = outW + q * 128 + k8 * 8;
        #pragma unroll
        for (int j = 0; j < 8; ++j) s += (float)hr[k8][j] * wr[j];
    }
    s += __shfl_down(s, 2);
    s += __shfl_down(s, 1);
    if (q == 0) {
        float p = s + outb[0];
        pred_s[row] = p;
        if (nt == 0) dout[(size_t)b * HOR + oidx] = p;
    }
    __syncthreads();
}

// ---------------------------------------------------------------------------
struct PArgs {
    const f16 *wh0, *wih1, *whh1, *dwh0, *dwih1, *dwhh1;
    const float *x;
    const float *ebih0, *ebhh0, *ebih1, *ebhh1;
    const float *dbih0, *dbhh0, *dbih1, *dbhh1;
    const float *eWih0, *dWih0, *outW, *outb;
    f16 *h0ring, *h1ping, *h0dping, *h1dping;
    float *c0, *c1, *dout;
    int *f0, *f1, *fc0, *f0d, *f1d;   // epoch flags, [8 bt][32 nt] each
};

// Persistent kernel: 512 blocks (2/CU: 37.1KB LDS, 256 thr, launch_bounds(256,2)).
// bt = bid&7, role = (bid>>3)&1, nt = bid>>4  =>  all 64 blocks of a bt-group
// land on one XCD under round-robin bid%8 mapping (locality heuristic only;
// correctness comes from the LLC-coherent sc0sc1 data/flag path).
__global__ __launch_bounds__(256, 2)
void persist_k(PArgs a)
{
    __shared__ __align__(16) char smem[37120];
    float* pred_s = (float*)(smem + 36864);
    const size_t BH = (size_t)B * H;
    const int bid  = blockIdx.x;
    const int bt   = bid & 7;
    const int role = (bid >> 3) & 1;
    const int nt   = bid >> 4;
    int* const myf0  = a.f0  + bt * 32;
    int* const myf1  = a.f1  + bt * 32;
    int* const myfc0 = a.fc0 + bt * 32;
    int* const myf0d = a.f0d + bt * 32;
    int* const myf1d = a.f1d + bt * 32;

    if (role == 0) {
        // ---- encoder layer0: h0(t) = cell(x(t), h0(t-1)) ----
        for (int t = 0; t < T; ++t) {
            if (t >= 1) wait_group(myf0, t);        // h0(t-1) ready (all 32 cols)
            if (t >= 4) wait_group(myfc0, t - 3);   // ring slot consumed by layer1
            const f16* hp = a.h0ring + (size_t)((t + 3) & 3) * BH;
            f16* ho = a.h0ring + (size_t)(t & 3) * BH;
            if (t == 0)
                cell_body<0>(bt, nt, smem, hp, hp, a.wh0, a.wh0, a.ebih0, a.ebhh0,
                             1, a.x + (size_t)t * F, T * F, a.eWih0, nullptr, a.c0, ho);
            else
                cell_body<8>(bt, nt, smem, hp, hp, a.wh0, a.wh0, a.ebih0, a.ebhh0,
                             1, a.x + (size_t)t * F, T * F, a.eWih0, nullptr, a.c0, ho);
            __syncthreads();
            if (threadIdx.x == 0) FLAG_STORE(myf0 + nt, t + 1);
        }
        // ---- decoder layer0 (+ pred head) ----
        for (int td = 0; td <= HOR; ++td) {
            if (td == 0) {
                wait_group(myf0, T);                // own group enc done
            } else {
                wait_group(myf1d, td);              // h1d(td-1) ready
                compute_pred(bt, nt, a.h1dping + (size_t)((td + 1) & 1) * BH,
                             a.outW, a.outb, pred_s, a.dout, td - 1);
            }
            if (td == HOR) break;
            if (td >= 1) wait_group(myf0d, td);     // h0d(td-1) ready
            const f16* hp = (td == 0) ? a.h0ring + (size_t)3 * BH
                                      : a.h0dping + (size_t)((td + 1) & 1) * BH;
            if (td == 0)
                cell_body<8>(bt, nt, smem, hp, hp, a.dwh0, a.dwh0, a.dbih0, a.dbhh0,
                             2, a.x + (size_t)(T - 1) * F, T * F, a.dWih0, nullptr,
                             a.c0, a.h0dping);
            else
                cell_body<8>(bt, nt, smem, hp, hp, a.dwh0, a.dwh0, a.dbih0, a.dbhh0,
                             3, nullptr, 0, a.dWih0, pred_s,
                             a.c0, a.h0dping + (size_t)(td & 1) * BH);
            __syncthreads();
            if (threadIdx.x == 0) FLAG_STORE(myf0d + nt, td + 1);
        }
    } else {
        // ---- encoder layer1: h1(t) = cell([h0(t)|h1(t-1)]) ----
        for (int t = 0; t < T; ++t) {
            wait_group(myf0, t + 1);                // h0(t) ready
            if (t >= 1) wait_group(myf1, t);        // h1(t-1) ready
            const f16* a0 = a.h0ring + (size_t)(t & 3) * BH;
            const f16* a1 = a.h1ping + (size_t)((t + 1) & 1) * BH;
            f16* ho = a.h1ping + (size_t)(t & 1) * BH;
            if (t == 0)
                cell_body<8>(bt, nt, smem, a0, a0, a.wih1, a.wih1, a.ebih1, a.ebhh1,
                             0, nullptr, 0, nullptr, nullptr, a.c1, ho);
            else
                cell_body<16>(bt, nt, smem, a0, a1, a.wih1, a.whh1, a.ebih1, a.ebhh1,
                              0, nullptr, 0, nullptr, nullptr, a.c1, ho);
            __syncthreads();
            if (threadIdx.x == 0) {
                FLAG_STORE(myf1 + nt, t + 1);       // vmcnt(0) inside orders h stores
                FLAG_STORE_NW(myfc0 + nt, t + 1);   // ring-consumption signal
            }
        }
        // ---- decoder layer1 ----
        for (int td = 0; td < HOR; ++td) {
            wait_group(myf0d, td + 1);              // h0d(td) ready
            const f16* a1;
            if (td == 0) { wait_group(myf1, T);   a1 = a.h1ping + BH; }
            else         { wait_group(myf1d, td); a1 = a.h1dping + (size_t)((td + 1) & 1) * BH; }
            cell_body<16>(bt, nt, smem, a.h0dping + (size_t)(td & 1) * BH, a1,
                          a.dwih1, a.dwhh1, a.dbih1, a.dbhh1,
                          0, nullptr, 0, nullptr, nullptr,
                          a.c1, a.h1dping + (size_t)(td & 1) * BH);
            __syncthreads();
            if (threadIdx.x == 0) FLAG_STORE(myf1d + nt, td + 1);
        }
    }
}

// ---------------------------------------------------------------------------
extern "C" void kernel_launch(void* const* d_in, const int* in_sizes, int n_in,
                              void* d_out, int out_size, void* d_ws, size_t ws_size,
                              hipStream_t stream)
{
    const float* x     = (const float*)d_in[0];
    const float* eWih0 = (const float*)d_in[1];
    const float* eWhh0 = (const float*)d_in[2];
    const float* ebih0 = (const float*)d_in[3];
    const float* ebhh0 = (const float*)d_in[4];
    const float* eWih1 = (const float*)d_in[5];
    const float* eWhh1 = (const float*)d_in[6];
    const float* ebih1 = (const float*)d_in[7];
    const float* ebhh1 = (const float*)d_in[8];
    const float* dWih0 = (const float*)d_in[9];
    const float* dWhh0 = (const float*)d_in[10];
    const float* dbih0 = (const float*)d_in[11];
    const float* dbhh0 = (const float*)d_in[12];
    const float* dWih1 = (const float*)d_in[13];
    const float* dWhh1 = (const float*)d_in[14];
    const float* dbih1 = (const float*)d_in[15];
    const float* dbhh1 = (const float*)d_in[16];
    const float* outW  = (const float*)d_in[17];
    const float* outb  = (const float*)d_in[18];

    const size_t WSZ = (size_t)4 * H * H;   // halfs per converted weight
    const size_t BH  = (size_t)B * H;

    char* wsb = (char*)d_ws;
    size_t off = 0;
    f16* wh[6];
    for (int i = 0; i < 6; ++i) { wh[i] = (f16*)(wsb + off); off += WSZ * sizeof(f16); }
    f16* h0ring  = (f16*)(wsb + off); off += 4 * BH * sizeof(f16);
    f16* h1ping  = (f16*)(wsb + off); off += 2 * BH * sizeof(f16);
    f16* h0dping = (f16*)(wsb + off); off += 2 * BH * sizeof(f16);
    f16* h1dping = (f16*)(wsb + off); off += 2 * BH * sizeof(f16);
    float* c0    = (float*)(wsb + off); off += BH * sizeof(float);
    float* c1    = (float*)(wsb + off); off += BH * sizeof(float);
    size_t coff  = off;
    int* f0      = (int*)(wsb + off); off += 8 * 32 * sizeof(int);
    int* f1      = (int*)(wsb + off); off += 8 * 32 * sizeof(int);
    int* fc0     = (int*)(wsb + off); off += 8 * 32 * sizeof(int);
    int* f0d     = (int*)(wsb + off); off += 8 * 32 * sizeof(int);
    int* f1d     = (int*)(wsb + off); off += 8 * 32 * sizeof(int);
    size_t cbytes = off - coff;

    // fp16 weight conversion (permuted layout) + state/flag init, every call
    wconv_k<<<dim3(512, 6), 256, 0, stream>>>(eWhh0, wh[0], eWih1, wh[1], eWhh1, wh[2],
                                              dWhh0, wh[3], dWih1, wh[4], dWhh1, wh[5]);
    hipMemsetAsync(c0, 0, BH * sizeof(float), stream);
    hipMemsetAsync(c1, 0, BH * sizeof(float), stream);
    hipMemsetAsync((char*)wsb + coff, 0, cbytes, stream);

    PArgs a;
    a.wh0 = wh[0]; a.wih1 = wh[1]; a.whh1 = wh[2];
    a.dwh0 = wh[3]; a.dwih1 = wh[4]; a.dwhh1 = wh[5];
    a.x = x;
    a.ebih0 = ebih0; a.ebhh0 = ebhh0; a.ebih1 = ebih1; a.ebhh1 = ebhh1;
    a.dbih0 = dbih0; a.dbhh0 = dbhh0; a.dbih1 = dbih1; a.dbhh1 = dbhh1;
    a.eWih0 = eWih0; a.dWih0 = dWih0; a.outW = outW; a.outb = outb;
    a.h0ring = h0ring; a.h1ping = h1ping; a.h0dping = h0dping; a.h1dping = h1dping;
    a.c0 = c0; a.c1 = c1; a.dout = (float*)d_out;
    a.f0 = f0; a.f1 = f1; a.fc0 = fc0; a.f0d = f0d; a.f1d = f1d;

    persist_k<<<dim3(512), dim3(256), 0, stream>>>(a);
}

// Round 7
// 5120.823 us; speedup vs baseline: 2.4695x; 1.1640x over previous
//
#include <hip/hip_runtime.h>
#include <math.h>

constexpr int H   = 512;
constexpr int B   = 512;
constexpr int T   = 256;
constexpr int F   = 8;
constexpr int HOR = 24;

typedef _Float16 f16;
typedef _Float16 f16x8 __attribute__((ext_vector_type(8)));
typedef float    f32x4 __attribute__((ext_vector_type(4)));

__device__ __forceinline__ float sigm(float x) { return 1.0f / (1.0f + expf(-x)); }

// ---------------------------------------------------------------------------
// LLC-coherent (cross-XCD) access path: sc0 sc1 bypasses L1/L2, data lives in
// the shared Infinity Cache. Used for ALL h-tile and flag traffic. Weights /
// x / biases / c stay on the normal cached path (L2 never invalidated).
// 16 strided 16B loads: two 16B chunks per 128B K-chunk (offs k*128+{0,16}).
#define LLC_LOAD16S(base, r) \
  asm volatile( \
    "global_load_dwordx4 %0,  %16, off sc0 sc1\n\t" \
    "global_load_dwordx4 %1,  %16, off offset:16 sc0 sc1\n\t" \
    "global_load_dwordx4 %2,  %16, off offset:128 sc0 sc1\n\t" \
    "global_load_dwordx4 %3,  %16, off offset:144 sc0 sc1\n\t" \
    "global_load_dwordx4 %4,  %16, off offset:256 sc0 sc1\n\t" \
    "global_load_dwordx4 %5,  %16, off offset:272 sc0 sc1\n\t" \
    "global_load_dwordx4 %6,  %16, off offset:384 sc0 sc1\n\t" \
    "global_load_dwordx4 %7,  %16, off offset:400 sc0 sc1\n\t" \
    "global_load_dwordx4 %8,  %16, off offset:512 sc0 sc1\n\t" \
    "global_load_dwordx4 %9,  %16, off offset:528 sc0 sc1\n\t" \
    "global_load_dwordx4 %10, %16, off offset:640 sc0 sc1\n\t" \
    "global_load_dwordx4 %11, %16, off offset:656 sc0 sc1\n\t" \
    "global_load_dwordx4 %12, %16, off offset:768 sc0 sc1\n\t" \
    "global_load_dwordx4 %13, %16, off offset:784 sc0 sc1\n\t" \
    "global_load_dwordx4 %14, %16, off offset:896 sc0 sc1\n\t" \
    "global_load_dwordx4 %15, %16, off offset:912 sc0 sc1" \
    : "=v"(r[0]), "=v"(r[1]), "=v"(r[2]), "=v"(r[3]), \
      "=v"(r[4]), "=v"(r[5]), "=v"(r[6]), "=v"(r[7]), \
      "=v"(r[8]), "=v"(r[9]), "=v"(r[10]), "=v"(r[11]), \
      "=v"(r[12]), "=v"(r[13]), "=v"(r[14]), "=v"(r[15]) \
    : "v"(base))

// 16 contiguous 16B loads (256B run) for the pred head.
#define LLC_LOAD16C(base, r) \
  asm volatile( \
    "global_load_dwordx4 %0,  %16, off sc0 sc1\n\t" \
    "global_load_dwordx4 %1,  %16, off offset:16 sc0 sc1\n\t" \
    "global_load_dwordx4 %2,  %16, off offset:32 sc0 sc1\n\t" \
    "global_load_dwordx4 %3,  %16, off offset:48 sc0 sc1\n\t" \
    "global_load_dwordx4 %4,  %16, off offset:64 sc0 sc1\n\t" \
    "global_load_dwordx4 %5,  %16, off offset:80 sc0 sc1\n\t" \
    "global_load_dwordx4 %6,  %16, off offset:96 sc0 sc1\n\t" \
    "global_load_dwordx4 %7,  %16, off offset:112 sc0 sc1\n\t" \
    "global_load_dwordx4 %8,  %16, off offset:128 sc0 sc1\n\t" \
    "global_load_dwordx4 %9,  %16, off offset:144 sc0 sc1\n\t" \
    "global_load_dwordx4 %10, %16, off offset:160 sc0 sc1\n\t" \
    "global_load_dwordx4 %11, %16, off offset:176 sc0 sc1\n\t" \
    "global_load_dwordx4 %12, %16, off offset:192 sc0 sc1\n\t" \
    "global_load_dwordx4 %13, %16, off offset:208 sc0 sc1\n\t" \
    "global_load_dwordx4 %14, %16, off offset:224 sc0 sc1\n\t" \
    "global_load_dwordx4 %15, %16, off offset:240 sc0 sc1" \
    : "=v"(r[0]), "=v"(r[1]), "=v"(r[2]), "=v"(r[3]), \
      "=v"(r[4]), "=v"(r[5]), "=v"(r[6]), "=v"(r[7]), \
      "=v"(r[8]), "=v"(r[9]), "=v"(r[10]), "=v"(r[11]), \
      "=v"(r[12]), "=v"(r[13]), "=v"(r[14]), "=v"(r[15]) \
    : "v"(base))

// Drain vmcnt and ORDER all subsequent uses of r[] after it ("+v" ties).
#define VWAIT16(r) \
  asm volatile("s_waitcnt vmcnt(0)" \
    : "+v"(r[0]), "+v"(r[1]), "+v"(r[2]), "+v"(r[3]), \
      "+v"(r[4]), "+v"(r[5]), "+v"(r[6]), "+v"(r[7]), \
      "+v"(r[8]), "+v"(r[9]), "+v"(r[10]), "+v"(r[11]), \
      "+v"(r[12]), "+v"(r[13]), "+v"(r[14]), "+v"(r[15]) :: "memory")

// h-element write-through store (2B).
#define LLC_STORE_SHORT(p, v) \
  asm volatile("global_store_short %0, %1, off sc0 sc1" :: "v"(p), "v"(v) : "memory")

// Release-ish flag store: all prior stores (h, sc0sc1 write-through) reach the
// LLC before the flag becomes visible there. No cache-maintenance ops.
#define FLAG_STORE(p, v) \
  asm volatile("s_waitcnt vmcnt(0)\n\t" \
               "global_store_dword %0, %1, off sc0 sc1" :: "v"(p), "v"(v) : "memory")
#define FLAG_STORE_NW(p, v) \
  asm volatile("global_store_dword %0, %1, off sc0 sc1" :: "v"(p), "v"(v) : "memory")

// ---------------------------------------------------------------------------
// Weight convert: fp32 [4H][H] gate-major rows (row = g*H + jh) -> fp16
// [2048][512] permuted rows n' = jh*4 + g. grid (512, 6).
__global__ __launch_bounds__(256)
void wconv_k(const float* __restrict__ s0, f16* __restrict__ d0,
             const float* __restrict__ s1, f16* __restrict__ d1,
             const float* __restrict__ s2, f16* __restrict__ d2,
             const float* __restrict__ s3, f16* __restrict__ d3,
             const float* __restrict__ s4, f16* __restrict__ d4,
             const float* __restrict__ s5, f16* __restrict__ d5)
{
    const float* src; f16* dst;
    switch (blockIdx.y) {
        case 0:  src = s0; dst = d0; break;
        case 1:  src = s1; dst = d1; break;
        case 2:  src = s2; dst = d2; break;
        case 3:  src = s3; dst = d3; break;
        case 4:  src = s4; dst = d4; break;
        default: src = s5; dst = d5; break;
    }
    int idx = (blockIdx.x * 256 + threadIdx.x) * 8;
    int np  = idx >> 9;
    int k   = idx & 511;
    int jh  = np >> 2, g = np & 3;
    const float* sp = src + (size_t)(g * H + jh) * H + k;
    f16 tmp[8];
    #pragma unroll
    for (int j = 0; j < 8; ++j) tmp[j] = (f16)sp[j];
    *(f16x8*)(dst + idx) = *(const f16x8*)tmp;
}

// ---------------------------------------------------------------------------
// Poll 32 per-producer epoch flags with LLC loads (no fences, no L2 inv).
// Backoff after 8 failed polls to reduce fabric pressure from spinners.
__device__ __forceinline__ void wait_group(const int* f, int target)
{
    if (threadIdx.x < 64) {
        const int* p = f + (threadIdx.x & 31);
        bool ok;
        int it = 0;
        do {
            int v;
            asm volatile("global_load_dword %0, %1, off sc0 sc1\n\t"
                         "s_waitcnt vmcnt(0)"
                         : "=v"(v) : "v"(p) : "memory");
            ok = __all(v >= target);
            if (!ok) {
                if (it >= 8) __builtin_amdgcn_s_sleep(8);
                else         __builtin_amdgcn_s_sleep(1);
                ++it;
            }
        } while (!ok);
    }
    __syncthreads();
}

// ---------------------------------------------------------------------------
struct WChunk { f16x8 w0, w1; };

__device__ __forceinline__ WChunk loadW(int kt, const f16* __restrict__ W0,
                                        const f16* __restrict__ W1,
                                        int n0, int srow, int sch)
{
    const f16* Wp = (kt < 8) ? W0 : W1;
    const int  ko = ((kt < 8) ? kt : kt - 8) * 64;
    const f16* wp = Wp + (size_t)(n0 + srow) * H + ko + sch * 16;
    WChunk c;
    c.w0 = *(const f16x8*)wp;
    c.w1 = *(const f16x8*)(wp + 8);
    return c;
}

// Fused LSTM cell tile, 64 b-rows x 64 n', K = NKT*64 (NKT = 0, 8 or 16).
// A (h state) read via LLC loads prefetched to registers; W via cached loads
// (double-buffered LDS, compiler-pipelined; with nt->XCD mapping the W tiles
// are L2-resident so the 1-deep prefetch covers the ~200cyc L2 latency).
// xmode: 0 none; 1 enc0 F=8 fp32 x-path; 2 scalar from xptr[b*xstride];
// 3 scalar from LDS pred_s[bl].
template<int NKT>
__device__ __forceinline__ void cell_body(int bt, int nt, char* smem,
    const f16* __restrict__ A0, const f16* __restrict__ A1,
    const f16* __restrict__ W0, const f16* __restrict__ W1,
    const float* __restrict__ bih, const float* __restrict__ bhh,
    int xmode, const float* __restrict__ xptr, int xstride,
    const float* __restrict__ xw, const float* __restrict__ pred_s,
    float* __restrict__ cst, f16* __restrict__ hout)
{
    constexpr int ABUF = 64 * 72;                  // halfs per buffer slot
    f16*   As = (f16*)smem;                        // [2][64][72]
    f16*   Ws = (f16*)smem + 2 * ABUF;             // [2][64][72]
    float* zs = (float*)smem;                      // overlay after K-loop

    const int tid  = threadIdx.x;
    const int lane = tid & 63;
    const int wv   = tid >> 6;
    const int wm   = wv & 1;
    const int wn   = wv >> 1;
    const int r    = lane & 15;
    const int g4   = lane >> 4;
    const int b0   = bt * 64;
    const int n0   = nt * 64;
    const int jh0  = nt * 16;
    const int srow = tid >> 2, sch = tid & 3;

    f32x4 acc[2][2] = {};

    if constexpr (NKT > 0) {
        f16x8 ar[16];          // K-half 0 (A0), all 16 chunks of this thread's row
        f16x8 br[16];          // K-half 1 (A1), NKT==16 only
        const f16* ap = A0 + (size_t)(b0 + srow) * H + sch * 16;
        LLC_LOAD16S(ap, ar);
        if constexpr (NKT == 16) {
            const f16* bp = A1 + (size_t)(b0 + srow) * H + sch * 16;
            LLC_LOAD16S(bp, br);
        }
        VWAIT16(ar);           // drains all outstanding (incl. br group)

        WChunk wcur = loadW(0, W0, W1, n0, srow, sch);
        #pragma unroll
        for (int kt = 0; kt < NKT; ++kt) {
            if (kt == 8) VWAIT16(br);              // ordering formality (already arrived)
            f16* Ab = As + (kt & 1) * ABUF;
            f16* Wb = Ws + (kt & 1) * ABUF;
            f16x8 a0v = (kt < 8) ? ar[kt * 2]     : br[(kt - 8) * 2];
            f16x8 a1v = (kt < 8) ? ar[kt * 2 + 1] : br[(kt - 8) * 2 + 1];
            *(f16x8*)(Ab + srow * 72 + sch * 16)     = a0v;
            *(f16x8*)(Ab + srow * 72 + sch * 16 + 8) = a1v;
            *(f16x8*)(Wb + srow * 72 + sch * 16)     = wcur.w0;
            *(f16x8*)(Wb + srow * 72 + sch * 16 + 8) = wcur.w1;
            __syncthreads();

            WChunk wnxt = wcur;
            if (kt + 1 < NKT) wnxt = loadW(kt + 1, W0, W1, n0, srow, sch);

            #pragma unroll
            for (int sub = 0; sub < 2; ++sub) {
                f16x8 bf0 = *(const f16x8*)(Wb + (wn * 32 + r)      * 72 + sub * 32 + g4 * 8);
                f16x8 bf1 = *(const f16x8*)(Wb + (wn * 32 + 16 + r) * 72 + sub * 32 + g4 * 8);
                f16x8 af0 = *(const f16x8*)(Ab + (wm * 32 + r)      * 72 + sub * 32 + g4 * 8);
                f16x8 af1 = *(const f16x8*)(Ab + (wm * 32 + 16 + r) * 72 + sub * 32 + g4 * 8);
                acc[0][0] = __builtin_amdgcn_mfma_f32_16x16x32_f16(af0, bf0, acc[0][0], 0, 0, 0);
                acc[0][1] = __builtin_amdgcn_mfma_f32_16x16x32_f16(af0, bf1, acc[0][1], 0, 0, 0);
                acc[1][0] = __builtin_amdgcn_mfma_f32_16x16x32_f16(af1, bf0, acc[1][0], 0, 0, 0);
                acc[1][1] = __builtin_amdgcn_mfma_f32_16x16x32_f16(af1, bf1, acc[1][1], 0, 0, 0);
            }
            wcur = wnxt;
        }
    }

    __syncthreads();   // last frag reads drained before zs overlay
    #pragma unroll
    for (int fm = 0; fm < 2; ++fm)
        #pragma unroll
        for (int fn = 0; fn < 2; ++fn)
            #pragma unroll
            for (int j = 0; j < 4; ++j)
                zs[(wm * 32 + fm * 16 + g4 * 4 + j) * 68 +
                   (wn * 32 + fn * 16 + r)] = acc[fm][fn][j];
    __syncthreads();

    // epilogue: thread -> (4 b-rows, 1 jh); gates = 4 consecutive n'.
    const int jl = tid & 15;
    const int bq = tid >> 4;
    const int jh = jh0 + jl;

    float bsum[4];
    #pragma unroll
    for (int g = 0; g < 4; ++g) bsum[g] = bih[g * H + jh] + bhh[g * H + jh];

    #pragma unroll
    for (int bb = 0; bb < 4; ++bb) {
        const int bl = bq * 4 + bb;
        const int b  = b0 + bl;
        float4 z = *(const float4*)(zs + bl * 68 + jl * 4);
        float zi = z.x + bsum[0];
        float zf = z.y + bsum[1];
        float zg = z.z + bsum[2];
        float zo = z.w + bsum[3];
        if (xmode == 1) {
            const float* xr = xptr + (size_t)b * xstride;
            #pragma unroll
            for (int k = 0; k < F; ++k) {
                float xv = xr[k];
                zi += xv * xw[(0 * H + jh) * F + k];
                zf += xv * xw[(1 * H + jh) * F + k];
                zg += xv * xw[(2 * H + jh) * F + k];
                zo += xv * xw[(3 * H + jh) * F + k];
            }
        } else if (xmode == 2 || xmode == 3) {
            float xv = (xmode == 2) ? xptr[(size_t)b * xstride] : pred_s[bl];
            zi += xv * xw[0 * H + jh];
            zf += xv * xw[1 * H + jh];
            zg += xv * xw[2 * H + jh];
            zo += xv * xw[3 * H + jh];
        }
        size_t idx = (size_t)b * H + jh;
        float cold = cst[idx];                      // c is block-private: cached path
        float cn = sigm(zf) * cold + sigm(zi) * tanhf(zg);
        cst[idx] = cn;
        union { f16 h; unsigned short u; } cv;
        cv.h = (f16)(sigm(zo) * tanhf(cn));
        LLC_STORE_SHORT(hout + idx, (int)cv.u);     // h crosses blocks: LLC path
    }
}

// ---------------------------------------------------------------------------
// pred for 64 rows of this bt: pred_s[row] = h1row . outW + outb.
// All 32 nt blocks compute redundantly; only nt==0 writes d_out[., oidx].
__device__ __forceinline__ void compute_pred(int bt, int nt,
                             const f16* __restrict__ h1src,
                             const float* __restrict__ outW,
                             const float* __restrict__ outb,
                             float* pred_s, float* __restrict__ dout, int oidx)
{
    const int row = threadIdx.x >> 2;
    const int q   = threadIdx.x & 3;
    const int b   = bt * 64 + row;
    f16x8 hr[16];
    const f16* hp = h1src + (size_t)b * H + q * 128;
    LLC_LOAD16C(hp, hr);
    VWAIT16(hr);
    float s = 0.f;
    #pragma unroll
    for (int k8 = 0; k8 < 16; ++k8) {
        const float* wr = outW + q * 128 + k8 * 8;
        #pragma unroll
        for (int j = 0; j < 8; ++j) s += (float)hr[k8][j] * wr[j];
    }
    s += __shfl_down(s, 2);
    s += __shfl_down(s, 1);
    if (q == 0) {
        float p = s + outb[0];
        pred_s[row] = p;
        if (nt == 0) dout[(size_t)b * HOR + oidx] = p;
    }
    __syncthreads();
}

// ---------------------------------------------------------------------------
struct PArgs {
    const f16 *wh0, *wih1, *whh1, *dwh0, *dwih1, *dwhh1;
    const float *x;
    const float *ebih0, *ebhh0, *ebih1, *ebhh1;
    const float *dbih0, *dbhh0, *dbih1, *dbhh1;
    const float *eWih0, *dWih0, *outW, *outb;
    f16 *h0ring, *h1ping, *h0dping, *h1dping;
    float *c0, *c1, *dout;
    int *f0, *f1, *fc0, *f0d, *f1d;   // epoch flags, [8 bt][32 nt] each
};

// Persistent kernel: 512 blocks (2/CU: 37.1KB LDS, 256 thr, launch_bounds(256,2)).
// bid bits: [2:0]=nt&7 (XCD under round-robin bid%8), [3]=role, [6:4]=bt,
// [8:7]=nt>>3. Each XCD hosts nt tiles {x : x%8 == xcd} for ALL bt/roles ->
// per-XCD weight working set = 4 n'-tiles/layer = ~1.5MB << 4MB L2, so W stays
// L2-resident across all steps (locality heuristic only; correctness comes
// from the LLC-coherent sc0sc1 data/flag path).
__global__ __launch_bounds__(256, 2)
void persist_k(PArgs a)
{
    __shared__ __align__(16) char smem[37120];
    float* pred_s = (float*)(smem + 36864);
    const size_t BH = (size_t)B * H;
    const int bid  = blockIdx.x;
    const int ntl  = bid & 7;
    const int role = (bid >> 3) & 1;
    const int bt   = (bid >> 4) & 7;
    const int nt   = ntl | ((bid >> 7) << 3);
    int* const myf0  = a.f0  + bt * 32;
    int* const myf1  = a.f1  + bt * 32;
    int* const myfc0 = a.fc0 + bt * 32;
    int* const myf0d = a.f0d + bt * 32;
    int* const myf1d = a.f1d + bt * 32;

    if (role == 0) {
        // ---- encoder layer0: h0(t) = cell(x(t), h0(t-1)) ----
        for (int t = 0; t < T; ++t) {
            if (t >= 1) wait_group(myf0, t);        // h0(t-1) ready (all 32 cols)
            if (t >= 4) wait_group(myfc0, t - 3);   // ring slot consumed by layer1
            const f16* hp = a.h0ring + (size_t)((t + 3) & 3) * BH;
            f16* ho = a.h0ring + (size_t)(t & 3) * BH;
            if (t == 0)
                cell_body<0>(bt, nt, smem, hp, hp, a.wh0, a.wh0, a.ebih0, a.ebhh0,
                             1, a.x + (size_t)t * F, T * F, a.eWih0, nullptr, a.c0, ho);
            else
                cell_body<8>(bt, nt, smem, hp, hp, a.wh0, a.wh0, a.ebih0, a.ebhh0,
                             1, a.x + (size_t)t * F, T * F, a.eWih0, nullptr, a.c0, ho);
            __syncthreads();
            if (threadIdx.x == 0) FLAG_STORE(myf0 + nt, t + 1);
        }
        // ---- decoder layer0 (+ pred head) ----
        for (int td = 0; td <= HOR; ++td) {
            if (td == 0) {
                wait_group(myf0, T);                // own group enc done
            } else {
                wait_group(myf1d, td);              // h1d(td-1) ready
                compute_pred(bt, nt, a.h1dping + (size_t)((td + 1) & 1) * BH,
                             a.outW, a.outb, pred_s, a.dout, td - 1);
            }
            if (td == HOR) break;
            if (td >= 1) wait_group(myf0d, td);     // h0d(td-1) ready
            const f16* hp = (td == 0) ? a.h0ring + (size_t)3 * BH
                                      : a.h0dping + (size_t)((td + 1) & 1) * BH;
            if (td == 0)
                cell_body<8>(bt, nt, smem, hp, hp, a.dwh0, a.dwh0, a.dbih0, a.dbhh0,
                             2, a.x + (size_t)(T - 1) * F, T * F, a.dWih0, nullptr,
                             a.c0, a.h0dping);
            else
                cell_body<8>(bt, nt, smem, hp, hp, a.dwh0, a.dwh0, a.dbih0, a.dbhh0,
                             3, nullptr, 0, a.dWih0, pred_s,
                             a.c0, a.h0dping + (size_t)(td & 1) * BH);
            __syncthreads();
            if (threadIdx.x == 0) FLAG_STORE(myf0d + nt, td + 1);
        }
    } else {
        // ---- encoder layer1: h1(t) = cell([h0(t)|h1(t-1)]) ----
        for (int t = 0; t < T; ++t) {
            wait_group(myf0, t + 1);                // h0(t) ready
            if (t >= 1) wait_group(myf1, t);        // h1(t-1) ready
            const f16* a0 = a.h0ring + (size_t)(t & 3) * BH;
            const f16* a1 = a.h1ping + (size_t)((t + 1) & 1) * BH;
            f16* ho = a.h1ping + (size_t)(t & 1) * BH;
            if (t == 0)
                cell_body<8>(bt, nt, smem, a0, a0, a.wih1, a.wih1, a.ebih1, a.ebhh1,
                             0, nullptr, 0, nullptr, nullptr, a.c1, ho);
            else
                cell_body<16>(bt, nt, smem, a0, a1, a.wih1, a.whh1, a.ebih1, a.ebhh1,
                              0, nullptr, 0, nullptr, nullptr, a.c1, ho);
            __syncthreads();
            if (threadIdx.x == 0) {
                FLAG_STORE(myf1 + nt, t + 1);       // vmcnt(0) inside orders h stores
                FLAG_STORE_NW(myfc0 + nt, t + 1);   // ring-consumption signal
            }
        }
        // ---- decoder layer1 ----
        for (int td = 0; td < HOR; ++td) {
            wait_group(myf0d, td + 1);              // h0d(td) ready
            const f16* a1;
            if (td == 0) { wait_group(myf1, T);   a1 = a.h1ping + BH; }
            else         { wait_group(myf1d, td); a1 = a.h1dping + (size_t)((td + 1) & 1) * BH; }
            cell_body<16>(bt, nt, smem, a.h0dping + (size_t)(td & 1) * BH, a1,
                          a.dwih1, a.dwhh1, a.dbih1, a.dbhh1,
                          0, nullptr, 0, nullptr, nullptr,
                          a.c1, a.h1dping + (size_t)(td & 1) * BH);
            __syncthreads();
            if (threadIdx.x == 0) FLAG_STORE(myf1d + nt, td + 1);
        }
    }
}

// ---------------------------------------------------------------------------
extern "C" void kernel_launch(void* const* d_in, const int* in_sizes, int n_in,
                              void* d_out, int out_size, void* d_ws, size_t ws_size,
                              hipStream_t stream)
{
    const float* x     = (const float*)d_in[0];
    const float* eWih0 = (const float*)d_in[1];
    const float* eWhh0 = (const float*)d_in[2];
    const float* ebih0 = (const float*)d_in[3];
    const float* ebhh0 = (const float*)d_in[4];
    const float* eWih1 = (const float*)d_in[5];
    const float* eWhh1 = (const float*)d_in[6];
    const float* ebih1 = (const float*)d_in[7];
    const float* ebhh1 = (const float*)d_in[8];
    const float* dWih0 = (const float*)d_in[9];
    const float* dWhh0 = (const float*)d_in[10];
    const float* dbih0 = (const float*)d_in[11];
    const float* dbhh0 = (const float*)d_in[12];
    const float* dWih1 = (const float*)d_in[13];
    const float* dWhh1 = (const float*)d_in[14];
    const float* dbih1 = (const float*)d_in[15];
    const float* dbhh1 = (const float*)d_in[16];
    const float* outW  = (const float*)d_in[17];
    const float* outb  = (const float*)d_in[18];

    const size_t WSZ = (size_t)4 * H * H;   // halfs per converted weight
    const size_t BH  = (size_t)B * H;

    char* wsb = (char*)d_ws;
    size_t off = 0;
    f16* wh[6];
    for (int i = 0; i < 6; ++i) { wh[i] = (f16*)(wsb + off); off += WSZ * sizeof(f16); }
    f16* h0ring  = (f16*)(wsb + off); off += 4 * BH * sizeof(f16);
    f16* h1ping  = (f16*)(wsb + off); off += 2 * BH * sizeof(f16);
    f16* h0dping = (f16*)(wsb + off); off += 2 * BH * sizeof(f16);
    f16* h1dping = (f16*)(wsb + off); off += 2 * BH * sizeof(f16);
    float* c0    = (float*)(wsb + off); off += BH * sizeof(float);
    float* c1    = (float*)(wsb + off); off += BH * sizeof(float);
    size_t coff  = off;
    int* f0      = (int*)(wsb + off); off += 8 * 32 * sizeof(int);
    int* f1      = (int*)(wsb + off); off += 8 * 32 * sizeof(int);
    int* fc0     = (int*)(wsb + off); off += 8 * 32 * sizeof(int);
    int* f0d     = (int*)(wsb + off); off += 8 * 32 * sizeof(int);
    int* f1d     = (int*)(wsb + off); off += 8 * 32 * sizeof(int);
    size_t cbytes = off - coff;

    // fp16 weight conversion (permuted layout) + state/flag init, every call
    wconv_k<<<dim3(512, 6), 256, 0, stream>>>(eWhh0, wh[0], eWih1, wh[1], eWhh1, wh[2],
                                              dWhh0, wh[3], dWih1, wh[4], dWhh1, wh[5]);
    hipMemsetAsync(c0, 0, BH * sizeof(float), stream);
    hipMemsetAsync(c1, 0, BH * sizeof(float), stream);
    hipMemsetAsync((char*)wsb + coff, 0, cbytes, stream);

    PArgs a;
    a.wh0 = wh[0]; a.wih1 = wh[1]; a.whh1 = wh[2];
    a.dwh0 = wh[3]; a.dwih1 = wh[4]; a.dwhh1 = wh[5];
    a.x = x;
    a.ebih0 = ebih0; a.ebhh0 = ebhh0; a.ebih1 = ebih1; a.ebhh1 = ebhh1;
    a.dbih0 = dbih0; a.dbhh0 = dbhh0; a.dbih1 = dbih1; a.dbhh1 = dbhh1;
    a.eWih0 = eWih0; a.dWih0 = dWih0; a.outW = outW; a.outb = outb;
    a.h0ring = h0ring; a.h1ping = h1ping; a.h0dping = h0dping; a.h1dping = h1dping;
    a.c0 = c0; a.c1 = c1; a.dout = (float*)d_out;
    a.f0 = f0; a.f1 = f1; a.fc0 = fc0; a.f0d = f0d; a.f1d = f1d;

    persist_k<<<dim3(512), dim3(256), 0, stream>>>(a);
}